// Round 11
// baseline (75.769 us; speedup 1.0000x reference)
//
#include <hip/hip_runtime.h>
#include <math.h>

#define HW 262144            // 512*512
#define TOTAL 12582912       // 48 planes * HW
#define TS 32
#define NT 512               // threads per block
#define P 2                  // planes per block, element-interleaved as float2
#define NGROUP 24            // 48 / P

#define CR 0.8910065241883679f   // cos(27 deg)
#define SR 0.45399049973954675f  // sin(27 deg)

#define K5CX (255.5f * (1.0f - CR + SR))
#define K5CY (255.5f * (1.0f - SR - CR))

// Fixed padded region dims (>= max true span at any tile position)
#define W2 52
#define H2 44
#define W3 46
#define H3 45
#define W4 49
#define H4 48
#define W5 36
#define H5 35
#define BUFA_SZ 2352   // float2 cells: max(W2*H2=2288, W4*H4=2352); holds R5 in fast path
#define BUFB_SZ 2070   // float2 cells: max(W3*H3=2070, W5*H5=1260); holds R3 in fast path

struct Box { int x0, x1, y0, y1; };

__device__ __forceinline__ Box back_box(Box d, float A, float B, float C,
                                        float D, float E, float F) {
    float xa = (float)d.x0, xb = (float)d.x1, ya = (float)d.y0, yb = (float)d.y1;
    float mnx = fminf(A * xa, A * xb) + fminf(B * ya, B * yb) + C;
    float mxx = fmaxf(A * xa, A * xb) + fmaxf(B * ya, B * yb) + C;
    float mny = fminf(D * xa, D * xb) + fminf(E * ya, E * yb) + F;
    float mxy = fmaxf(D * xa, D * xb) + fmaxf(E * ya, E * yb) + F;
    Box s;
    s.x0 = (int)floorf(mnx); s.x1 = (int)floorf(mxx) + 1;
    s.y0 = (int)floorf(mny); s.y1 = (int)floorf(mxy) + 1;
    return s;
}

__device__ __forceinline__ float2 lerp2(float w, float2 a, float2 b) {
    float2 r;
    r.x = fmaf(w, b.x - a.x, a.x);
    r.y = fmaf(w, b.y - a.y, a.y);
    return r;
}

// ================= FAST (interior) PATH =================

// s23: scale(s3) ∘ translate+mirror(s2) as exact separable 3x3 from GLOBAL -> bufB(R3).
// S2[x,y] = 0.64 I[496-x] + 0.36 I[495-x] (cols), rows y-11 (0.24), y-10 (0.76).
// s3 bilinear over S2 => 3-tap x: u0=0.64-0.64wx @496-x0, u1=0.36+0.28wx @495-x0,
// u2=0.36wx @494-x0; 3-tap y: t0=0.24-0.24wy @y0-11, t1=0.76-0.52wy @y0-10, t2=0.76wy @y0-9.
__device__ __forceinline__ void s23_eval(int i, const float* __restrict__ gin,
                                         float2* __restrict__ dst, int r3x0, int r3y0)
{
    int ly = i / W3;
    int lx = i - ly * W3;
    float px = (float)(r3x0 + lx), py = (float)(r3y0 + ly);
    float fx = fmaf(1.1f, px, -25.55f);
    float fy = fmaf(0.95f, py, 12.775f);
    float xf = floorf(fx), yf = floorf(fy);
    float wx = fx - xf, wy = fy - yf;
    int x0 = (int)xf, y0 = (int)yf;
    int off = ((y0 - 11) << 9) + (496 - x0);   // interior guarantees all 9 taps in-image
    const float* g0 = gin + off;
    const float* g1 = g0 + HW;
    float u0 = fmaf(-0.64f, wx, 0.64f);
    float u1 = fmaf(0.28f, wx, 0.36f);
    float u2 = 0.36f * wx;
    float t0 = fmaf(-0.24f, wy, 0.24f);
    float t1 = fmaf(-0.52f, wy, 0.76f);
    float t2 = 0.76f * wy;
    float a0 = g0[0],    a1 = g0[-1],   a2 = g0[-2];
    float a3 = g0[512],  a4 = g0[511],  a5 = g0[510];
    float a6 = g0[1024], a7 = g0[1023], a8 = g0[1022];
    float b0 = g1[0],    b1 = g1[-1],   b2 = g1[-2];
    float b3 = g1[512],  b4 = g1[511],  b5 = g1[510];
    float b6 = g1[1024], b7 = g1[1023], b8 = g1[1022];
    float r0a = fmaf(u0, a0, fmaf(u1, a1, u2 * a2));
    float r1a = fmaf(u0, a3, fmaf(u1, a4, u2 * a5));
    float r2a = fmaf(u0, a6, fmaf(u1, a7, u2 * a8));
    float r0b = fmaf(u0, b0, fmaf(u1, b1, u2 * b2));
    float r1b = fmaf(u0, b3, fmaf(u1, b4, u2 * b5));
    float r2b = fmaf(u0, b6, fmaf(u1, b7, u2 * b8));
    float2 o;
    o.x = fmaf(t0, r0a, fmaf(t1, r1a, t2 * r2a));
    o.y = fmaf(t0, r0b, fmaf(t1, r1b, t2 * r2b));
    dst[i] = o;
}

// s45: rotate(s5) ∘ zoom(s4) as exact 3x3 stencil on the R3 grid: bufB(R3) -> bufA(R5).
// s5 taps X=x5,x5+1 share x-kernels of s4 (2-tap each, bases bx, bx+dx) => 3-tap
// accumulated weights; same for y. Taps with possibly-out-of-box index have weight
// exactly 0 and are clamp-read (always in-buffer, finite).
__device__ __forceinline__ void s45_eval(int i, const float2* __restrict__ src,
                                         float2* __restrict__ dst,
                                         int r5x0, int r5y0, int r3x0, int r3y0)
{
    int ly = i / W5;
    int lx = i - ly * W5;
    float px = (float)(r5x0 + lx), py = (float)(r5y0 + ly);
    float fx5 = fmaf(CR, px, fmaf(-SR, py, K5CX));
    float fy5 = fmaf(SR, px, fmaf(CR, py, K5CY));
    float x5f = floorf(fx5), y5f = floorf(fy5);
    float wx5 = fx5 - x5f, wy5 = fy5 - y5f;

    // x-kernel: zoom coords of X=x5 and X=x5+1
    float fx40 = fmaf(0.9f, x5f, 25.55f);
    float bxf = floorf(fx40);  float w40 = fx40 - bxf;
    float fx41 = fx40 + 0.9f;
    float bx1f = floorf(fx41); float w41 = fx41 - bx1f;
    float mx = (bx1f == bxf) ? 1.0f : 0.0f;   // dx==0
    float iwx5 = 1.0f - wx5;
    float ax0 = iwx5 * (1.0f - w40), ax1 = iwx5 * w40;
    float bx0 = wx5 * (1.0f - w41),  bx1w = wx5 * w41;
    float cw0 = fmaf(mx, bx0, ax0);
    float cw1 = ax1 + fmaf(mx, bx1w, (1.0f - mx) * bx0);
    float cw2 = (1.0f - mx) * bx1w;

    // y-kernel
    float fy40 = fmaf(0.9f, y5f, 25.55f);
    float byf = floorf(fy40);  float v40 = fy40 - byf;
    float fy41 = fy40 + 0.9f;
    float by1f = floorf(fy41); float v41 = fy41 - by1f;
    float my = (by1f == byf) ? 1.0f : 0.0f;
    float iwy5 = 1.0f - wy5;
    float ay0 = iwy5 * (1.0f - v40), ay1 = iwy5 * v40;
    float by0 = wy5 * (1.0f - v41),  by1w = wy5 * v41;
    float rw0 = fmaf(my, by0, ay0);
    float rw1 = ay1 + fmaf(my, by1w, (1.0f - my) * by0);
    float rw2 = (1.0f - my) * by1w;

    int cb = min(max((int)bxf - r3x0, 0), W3 - 2);
    int rb = min(max((int)byf - r3y0, 0), H3 - 2);
    int c2 = min(cb + 2, W3 - 1);
    int r2 = min(rb + 2, H3 - 1);
    const float2* s0 = src + rb * W3;
    const float2* s1 = s0 + W3;
    const float2* s2 = src + r2 * W3;
    float2 A0 = s0[cb], A1 = s0[cb + 1], A2 = s0[c2];
    float2 B0 = s1[cb], B1 = s1[cb + 1], B2 = s1[c2];
    float2 C0 = s2[cb], C1 = s2[cb + 1], C2 = s2[c2];
    float rAx = fmaf(cw0, A0.x, fmaf(cw1, A1.x, cw2 * A2.x));
    float rAy = fmaf(cw0, A0.y, fmaf(cw1, A1.y, cw2 * A2.y));
    float rBx = fmaf(cw0, B0.x, fmaf(cw1, B1.x, cw2 * B2.x));
    float rBy = fmaf(cw0, B0.y, fmaf(cw1, B1.y, cw2 * B2.y));
    float rCx = fmaf(cw0, C0.x, fmaf(cw1, C1.x, cw2 * C2.x));
    float rCy = fmaf(cw0, C0.y, fmaf(cw1, C1.y, cw2 * C2.y));
    float2 o;
    o.x = fmaf(rw0, rAx, fmaf(rw1, rBx, rw2 * rCx));
    o.y = fmaf(rw0, rAy, fmaf(rw1, rBy, rw2 * rCy));
    dst[i] = o;
}

// ================= GENERIC (boundary) helpers — round-7 proven =================

__device__ __forceinline__ void s2_eval_gen(int i, const float* __restrict__ gin,
                                            float2* __restrict__ dst, int rx0, int ry0)
{
    int ly = i / W2;
    int lx = i - ly * W2;
    int pxi = rx0 + lx, pyi = ry0 + ly;
    float wx0m = ((unsigned)pxi <= 496u) ? 0.64f : 0.0f;
    float wx1m = ((unsigned)pxi <= 495u) ? 0.36f : 0.0f;
    float wy0m = ((unsigned)(pyi - 11) <= 500u) ? 0.24f : 0.0f;
    float wy1m = ((unsigned)(pyi - 10) <= 501u) ? 0.76f : 0.0f;
    int xc0 = min(max(496 - pxi, 0), 511);
    int xc1 = min(max(495 - pxi, 0), 511);
    int r0 = min(max(pyi - 11, 0), 511) << 9;
    int r1 = min(max(pyi - 10, 0), 511) << 9;
    float2 o;
    #pragma unroll
    for (int p = 0; p < P; ++p) {
        const float* g = gin + p * HW;
        float v00 = g[r0 + xc0], v01 = g[r0 + xc1];
        float v10 = g[r1 + xc0], v11 = g[r1 + xc1];
        float h0 = fmaf(wx1m, v01, wx0m * v00);
        float h1 = fmaf(wx1m, v11, wx0m * v10);
        float val = fmaf(wy1m, h1, wy0m * h0);
        if (p == 0) o.x = val; else o.y = val;
    }
    dst[i] = o;
}

template <int SW, int SH, int DW, bool AXIS>
__device__ __forceinline__ void lds_eval_gen(int i, float A, float B, float Cs,
    float D, float E, float Fs, const float2* __restrict__ src,
    float2* __restrict__ dst, int dx0, int dy0)
{
    int ly = i / DW;
    int lx = i - ly * DW;
    int pxi = dx0 + lx, pyi = dy0 + ly;
    float px = (float)pxi, py = (float)pyi;
    float fx = AXIS ? fmaf(A, px, Cs) : fmaf(A, px, fmaf(B, py, Cs));
    float fy = AXIS ? fmaf(E, py, Fs) : fmaf(D, px, fmaf(E, py, Fs));
    float xf = floorf(fx), yf = floorf(fy);
    float wx = fx - xf, wy = fy - yf;
    int x0 = min(max((int)xf, 0), SW - 2);
    int y0 = min(max((int)yf, 0), SH - 2);
    const float2* s = src + y0 * SW + x0;
    float2 v00 = s[0], v01 = s[1];
    float2 v10 = s[SW], v11 = s[SW + 1];
    float2 a0 = lerp2(wx, v00, v01);
    float2 a1 = lerp2(wx, v10, v11);
    float2 val = lerp2(wy, a0, a1);
    if ((unsigned)pxi >= 512u || (unsigned)pyi >= 512u) { val.x = 0.f; val.y = 0.f; }
    dst[i] = val;
}

template <int SW, int SH, int DW, int DTOT, bool AXIS>
__device__ __forceinline__ void stage_lds_gen(int tid, float A, float B, float Cs,
    float D, float E, float Fs, const float2* __restrict__ src,
    float2* __restrict__ dst, int dx0, int dy0)
{
    constexpr int FULL = DTOT / NT;
    constexpr int TAIL = DTOT - FULL * NT;
    #pragma unroll
    for (int k = 0; k < FULL; ++k)
        lds_eval_gen<SW, SH, DW, AXIS>(tid + k * NT, A, B, Cs, D, E, Fs,
                                       src, dst, dx0, dy0);
    if (TAIL && tid < TAIL)
        lds_eval_gen<SW, SH, DW, AXIS>(tid + FULL * NT, A, B, Cs, D, E, Fs,
                                       src, dst, dx0, dy0);
}

// stage 6 (shear): src(R5) -> global, 2 planes
template <bool INT>
__device__ __forceinline__ void s6_eval(int ii, const float2* __restrict__ src,
    float* __restrict__ go, int tx0, int ty0, int sx0, int sy0)
{
    int lx = ii & 31, ly = ii >> 5;
    float px = (float)(tx0 + lx), py = (float)(ty0 + ly);
    float fx = fmaf(0.05f, py, -12.775f - (float)sx0) + px;
    float fy = fmaf(-0.03f, px, 7.665f - (float)sy0) + py;
    float xf = floorf(fx), yf = floorf(fy);
    float wx = fx - xf, wy = fy - yf;
    int x0 = (int)xf, y0 = (int)yf;
    if (!INT) { x0 = min(max(x0, 0), W5 - 2); y0 = min(max(y0, 0), H5 - 2); }
    const float2* s = src + y0 * W5 + x0;
    float2 v00 = s[0], v01 = s[1];
    float2 v10 = s[W5], v11 = s[W5 + 1];
    float2 a0 = lerp2(wx, v00, v01);
    float2 a1 = lerp2(wx, v10, v11);
    float2 val = lerp2(wy, a0, a1);
    int gidx = (ty0 + ly) * 512 + tx0 + lx;
    __builtin_nontemporal_store(val.x, &go[gidx]);
    __builtin_nontemporal_store(val.y, &go[HW + gidx]);
}

// ---- interior tile: 3 phases, 2 barriers ----
__device__ __forceinline__ void img_tile_fast(int tid, const float* __restrict__ gin,
    float* __restrict__ go, int tx0, int ty0, Box R3, Box R5,
    float2* bufA, float2* bufB)
{
    // s23: global -> bufB(R3)
    {
        constexpr int FULL = (W3 * H3) / NT;          // 4
        constexpr int TAIL = W3 * H3 - FULL * NT;     // 22
        #pragma unroll
        for (int k = 0; k < FULL; ++k)
            s23_eval(tid + k * NT, gin, bufB, R3.x0, R3.y0);
        if (tid < TAIL) s23_eval(tid + FULL * NT, gin, bufB, R3.x0, R3.y0);
    }
    __syncthreads();
    // s45: bufB(R3) -> bufA(R5)
    {
        constexpr int FULL = (W5 * H5) / NT;          // 2
        constexpr int TAIL = W5 * H5 - FULL * NT;     // 236
        #pragma unroll
        for (int k = 0; k < FULL; ++k)
            s45_eval(tid + k * NT, bufB, bufA, R5.x0, R5.y0, R3.x0, R3.y0);
        if (tid < TAIL) s45_eval(tid + FULL * NT, bufB, bufA, R5.x0, R5.y0, R3.x0, R3.y0);
    }
    __syncthreads();
    // s6: bufA(R5) -> global tiles
    #pragma unroll
    for (int k = 0; k < (TS * TS) / NT; ++k)
        s6_eval<true>(tid + k * NT, bufA, go, tx0, ty0, R5.x0, R5.y0);
}

// ---- boundary tile: round-7 5-phase generic pipeline ----
__device__ __forceinline__ void img_tile_gen(int tid, const float* __restrict__ gin,
    float* __restrict__ go, int tx0, int ty0,
    Box R2, Box R3, Box R4, Box R5, float2* bufA, float2* bufB)
{
    {
        constexpr int FULL = (W2 * H2) / NT;
        constexpr int TAIL = W2 * H2 - FULL * NT;
        #pragma unroll
        for (int k = 0; k < FULL; ++k)
            s2_eval_gen(tid + k * NT, gin, bufA, R2.x0, R2.y0);
        if (tid < TAIL) s2_eval_gen(tid + FULL * NT, gin, bufA, R2.x0, R2.y0);
    }
    __syncthreads();
    stage_lds_gen<W2, H2, W3, W3 * H3, true>(tid,
        1.1f, 0.0f, -25.55f - (float)R2.x0,
        0.0f, 0.95f, 12.775f - (float)R2.y0, bufA, bufB, R3.x0, R3.y0);
    __syncthreads();
    stage_lds_gen<W3, H3, W4, W4 * H4, true>(tid,
        0.9f, 0.0f, 25.55f - (float)R3.x0,
        0.0f, 0.9f, 25.55f - (float)R3.y0, bufB, bufA, R4.x0, R4.y0);
    __syncthreads();
    stage_lds_gen<W4, H4, W5, W5 * H5, false>(tid,
        CR, -SR, K5CX - (float)R4.x0,
        SR,  CR, K5CY - (float)R4.y0, bufA, bufB, R5.x0, R5.y0);
    __syncthreads();
    #pragma unroll
    for (int k = 0; k < (TS * TS) / NT; ++k)
        s6_eval<false>(tid + k * NT, bufB, go, tx0, ty0, R5.x0, R5.y0);
}

// Compose the 6 nearest-neighbor integer maps (exact vs sequential resampling).
__global__ void compose_nearest_map(int* __restrict__ map) {
    int p = blockIdx.x * blockDim.x + threadIdx.x;
    if (p >= HW) return;
    const float TH[6][6] = {
        { 1.0f,  0.05f, 0.0f,  -0.03f, 1.0f,  0.0f },   // shear
        { CR,    -SR,   0.0f,   SR,    CR,    0.0f },   // rotate
        { 0.9f,  0.0f,  0.0f,   0.0f,  0.9f,  0.0f },   // zoom
        { 1.1f,  0.0f,  0.0f,   0.0f,  0.95f, 0.0f },   // scale
        { 1.0f,  0.0f,  0.06f,  0.0f,  1.0f, -0.04f },  // translate
        { -1.0f, 0.0f,  0.0f,   0.0f,  1.0f,  0.0f },   // mirror
    };
    int cx = p & 511, cy = p >> 9;
    bool valid = true;
    #pragma unroll
    for (int s = 0; s < 6; ++s) {
        if (!valid) break;
        float x = (cx + 0.5f) * (2.0f / 512.0f) - 1.0f;
        float y = (cy + 0.5f) * (2.0f / 512.0f) - 1.0f;
        float gx = TH[s][0] * x + TH[s][1] * y + TH[s][2];
        float gy = TH[s][3] * x + TH[s][4] * y + TH[s][5];
        float ix = ((gx + 1.0f) * 512.0f - 1.0f) * 0.5f;
        float iy = ((gy + 1.0f) * 512.0f - 1.0f) * 0.5f;
        float xr = rintf(ix), yr = rintf(iy);
        if (xr < 0.0f || xr > 511.0f || yr < 0.0f || yr > 511.0f) valid = false;
        else { cx = (int)xr; cy = (int)yr; }
    }
    map[p] = valid ? (cy * 512 + cx) : -1;
}

// One block per (plane-pair, 32x32 tile).
__global__ __launch_bounds__(NT, 8) void fused_all(
    const float* __restrict__ img, const float* __restrict__ lab,
    const int* __restrict__ map, float* __restrict__ oimg,
    float* __restrict__ olab)
{
    __shared__ float2 bufA[BUFA_SZ];
    __shared__ float2 bufB[BUFB_SZ];
    int tid = threadIdx.x;
    int b = blockIdx.x;
    int group = b >> 8, tile = b & 255;
    int tx0 = (tile & 15) * TS, ty0 = (tile >> 4) * TS;
    int pbase = group * P;
    const float* gin = img + pbase * HW;
    const float* lin = lab + pbase * HW;
    float* go = oimg + pbase * HW;
    float* lo = olab + pbase * HW;

    // ---- label tiles: one map read feeds both planes ----
    #pragma unroll
    for (int k = 0; k < (TS * TS) / NT; ++k) {
        int ii = tid + k * NT;
        int gidx = (ty0 + (ii >> 5)) * 512 + tx0 + (ii & 31);
        int m = map[gidx];
        float v0 = (m >= 0) ? lin[m] : 0.f;
        float v1 = (m >= 0) ? lin[HW + m] : 0.f;
        __builtin_nontemporal_store(v0, &lo[gidx]);
        __builtin_nontemporal_store(v1, &lo[HW + gidx]);
    }

    // ---- region chain (uniform across threads) ----
    Box R6 = {tx0, tx0 + TS - 1, ty0, ty0 + TS - 1};
    Box R5 = back_box(R6, 1.0f, 0.05f, -12.775f, -0.03f, 1.0f, 7.665f);   // shear
    R5.x1 = min(R5.x1, R5.x0 + W5 - 1); R5.y1 = min(R5.y1, R5.y0 + H5 - 1);
    Box R4 = back_box(R5, CR, -SR, K5CX, SR, CR, K5CY);                   // rotate
    R4.x1 = min(R4.x1, R4.x0 + W4 - 1); R4.y1 = min(R4.y1, R4.y0 + H4 - 1);
    Box R3 = back_box(R4, 0.9f, 0.0f, 25.55f, 0.0f, 0.9f, 25.55f);        // zoom
    R3.x1 = min(R3.x1, R3.x0 + W3 - 1); R3.y1 = min(R3.y1, R3.y0 + H3 - 1);
    Box R2 = back_box(R3, 1.1f, 0.0f, -25.55f, 0.0f, 0.95f, 12.775f);     // scale

    bool dead = (R2.x1 < 0 || R2.x0 > 511 || R2.y1 < 0 || R2.y0 > 511)
             || (R3.x1 < 0 || R3.x0 > 511 || R3.y1 < 0 || R3.y0 > 511)
             || (R4.x1 < 0 || R4.x0 > 511 || R4.y1 < 0 || R4.y0 > 511)
             || (R5.x1 < 0 || R5.x0 > 511 || R5.y1 < 0 || R5.y0 > 511);
    if (dead) {
        #pragma unroll
        for (int k = 0; k < (TS * TS) / NT; ++k) {
            int ii = tid + k * NT;
            int gidx = (ty0 + (ii >> 5)) * 512 + tx0 + (ii & 31);
            __builtin_nontemporal_store(0.f, &go[gidx]);
            __builtin_nontemporal_store(0.f, &go[HW + gidx]);
        }
        return;
    }

    // interior: every PADDED region cell has fully-valid taps & coords
    bool interior =
        R2.x0 >= 0 && R2.x0 + W2 - 1 <= 495 && R2.y0 >= 11 && R2.y0 + H2 - 1 <= 511 &&
        R3.x0 >= 0 && R3.x0 + W3 - 1 <= 511 && R3.y0 >= 0 && R3.y0 + H3 - 1 <= 511 &&
        R4.x0 >= 0 && R4.x0 + W4 - 1 <= 511 && R4.y0 >= 0 && R4.y0 + H4 - 1 <= 511 &&
        R5.x0 >= 0 && R5.x0 + W5 - 1 <= 511 && R5.y0 >= 0 && R5.y0 + H5 - 1 <= 511;

    if (interior)
        img_tile_fast(tid, gin, go, tx0, ty0, R3, R5, bufA, bufB);
    else
        img_tile_gen(tid, gin, go, tx0, ty0, R2, R3, R4, R5, bufA, bufB);
}

extern "C" void kernel_launch(void* const* d_in, const int* in_sizes, int n_in,
                              void* d_out, int out_size, void* d_ws, size_t ws_size,
                              hipStream_t stream) {
    const float* img_in = (const float*)d_in[0];
    const float* lab_in = (const float*)d_in[1];
    float* out_img = (float*)d_out;
    float* out_lab = (float*)d_out + TOTAL;
    int* map = (int*)d_ws;

    compose_nearest_map<<<(HW + 255) / 256, 256, 0, stream>>>(map);
    fused_all<<<NGROUP * 256, NT, 0, stream>>>(img_in, lab_in, map, out_img, out_lab);
}

// Round 12
// 71.748 us; speedup vs baseline: 1.0560x; 1.0560x over previous
//
#include <hip/hip_runtime.h>
#include <math.h>

#define HW 262144            // 512*512
#define TOTAL 12582912       // 48 planes * HW
#define TS 32
#define NT 512               // threads per block
#define P 2                  // planes per block, element-interleaved as float2
#define NGROUP 24            // 48 / P

#define CR 0.8910065241883679f   // cos(27 deg)
#define SR 0.45399049973954675f  // sin(27 deg)

#define K5CX (255.5f * (1.0f - CR + SR))
#define K5CY (255.5f * (1.0f - SR - CR))

// Fixed padded region dims (>= max true span at any tile position)
#define W2 52
#define H2 44
#define W3 46
#define H3 45
#define W4 49
#define H4 48
#define W5 36
#define H5 35
#define BUFA_SZ 2352   // float2 cells: max(W2*H2=2288, W4*H4=2352)
#define BUFB_SZ 2070   // float2 cells: max(W3*H3=2070, W5*H5=1260)

struct Box { int x0, x1, y0, y1; };

__device__ __forceinline__ Box back_box(Box d, float A, float B, float C,
                                        float D, float E, float F) {
    float xa = (float)d.x0, xb = (float)d.x1, ya = (float)d.y0, yb = (float)d.y1;
    float mnx = fminf(A * xa, A * xb) + fminf(B * ya, B * yb) + C;
    float mxx = fmaxf(A * xa, A * xb) + fmaxf(B * ya, B * yb) + C;
    float mny = fminf(D * xa, D * xb) + fminf(E * ya, E * yb) + F;
    float mxy = fmaxf(D * xa, D * xb) + fmaxf(E * ya, E * yb) + F;
    Box s;
    s.x0 = (int)floorf(mnx); s.x1 = (int)floorf(mxx) + 1;
    s.y0 = (int)floorf(mny); s.y1 = (int)floorf(mxy) + 1;
    return s;
}

__device__ __forceinline__ float2 lerp2(float w, float2 a, float2 b) {
    float2 r;
    r.x = fmaf(w, b.x - a.x, a.x);
    r.y = fmaf(w, b.y - a.y, a.y);
    return r;
}

// ---- s23 (FAST path): scale ∘ translate ∘ mirror as exact separable 3x3
// read directly from GLOBAL -> dst(R3). Verified on HW in round 11.
// S2[x,y] = 0.64 I[496-x] + 0.36 I[495-x] (cols), rows y-11 (0.24), y-10 (0.76);
// s3 bilinear over S2 => x-taps u0@496-x0, u1@495-x0, u2@494-x0 and
// y-taps t0@y0-11, t1@y0-10, t2@y0-9.
__device__ __forceinline__ void s23_eval(int i, const float* __restrict__ gin,
                                         float2* __restrict__ dst, int r3x0, int r3y0)
{
    int ly = i / W3;
    int lx = i - ly * W3;
    float px = (float)(r3x0 + lx), py = (float)(r3y0 + ly);
    float fx = fmaf(1.1f, px, -25.55f);
    float fy = fmaf(0.95f, py, 12.775f);
    float xf = floorf(fx), yf = floorf(fy);
    float wx = fx - xf, wy = fy - yf;
    int x0 = (int)xf, y0 = (int)yf;
    int off = ((y0 - 11) << 9) + (496 - x0);   // interior guarantees all 9 taps in-image
    const float* g0 = gin + off;
    const float* g1 = g0 + HW;
    float u0 = fmaf(-0.64f, wx, 0.64f);
    float u1 = fmaf(0.28f, wx, 0.36f);
    float u2 = 0.36f * wx;
    float t0 = fmaf(-0.24f, wy, 0.24f);
    float t1 = fmaf(-0.52f, wy, 0.76f);
    float t2 = 0.76f * wy;
    float a0 = g0[0],    a1 = g0[-1],   a2 = g0[-2];
    float a3 = g0[512],  a4 = g0[511],  a5 = g0[510];
    float a6 = g0[1024], a7 = g0[1023], a8 = g0[1022];
    float b0 = g1[0],    b1 = g1[-1],   b2 = g1[-2];
    float b3 = g1[512],  b4 = g1[511],  b5 = g1[510];
    float b6 = g1[1024], b7 = g1[1023], b8 = g1[1022];
    float r0a = fmaf(u0, a0, fmaf(u1, a1, u2 * a2));
    float r1a = fmaf(u0, a3, fmaf(u1, a4, u2 * a5));
    float r2a = fmaf(u0, a6, fmaf(u1, a7, u2 * a8));
    float r0b = fmaf(u0, b0, fmaf(u1, b1, u2 * b2));
    float r1b = fmaf(u0, b3, fmaf(u1, b4, u2 * b5));
    float r2b = fmaf(u0, b6, fmaf(u1, b7, u2 * b8));
    float2 o;
    o.x = fmaf(t0, r0a, fmaf(t1, r1a, t2 * r2a));
    o.y = fmaf(t0, r0b, fmaf(t1, r1b, t2 * r2b));
    dst[i] = o;
}

// ---- stage 2 (GENERIC path): translate+mirror blend, full validity ----
__device__ __forceinline__ void s2_eval_gen(int i, const float* __restrict__ gin,
                                            float2* __restrict__ dst, int rx0, int ry0)
{
    int ly = i / W2;
    int lx = i - ly * W2;
    int pxi = rx0 + lx, pyi = ry0 + ly;
    float wx0m = ((unsigned)pxi <= 496u) ? 0.64f : 0.0f;
    float wx1m = ((unsigned)pxi <= 495u) ? 0.36f : 0.0f;
    float wy0m = ((unsigned)(pyi - 11) <= 500u) ? 0.24f : 0.0f;
    float wy1m = ((unsigned)(pyi - 10) <= 501u) ? 0.76f : 0.0f;
    int xc0 = min(max(496 - pxi, 0), 511);
    int xc1 = min(max(495 - pxi, 0), 511);
    int r0 = min(max(pyi - 11, 0), 511) << 9;
    int r1 = min(max(pyi - 10, 0), 511) << 9;
    float2 o;
    #pragma unroll
    for (int p = 0; p < P; ++p) {
        const float* g = gin + p * HW;
        float v00 = g[r0 + xc0], v01 = g[r0 + xc1];
        float v10 = g[r1 + xc0], v11 = g[r1 + xc1];
        float h0 = fmaf(wx1m, v01, wx0m * v00);
        float h1 = fmaf(wx1m, v11, wx0m * v10);
        float val = fmaf(wy1m, h1, wy0m * h0);
        if (p == 0) o.x = val; else o.y = val;
    }
    dst[i] = o;
}

// ---- LDS -> LDS bilinear stage (round-7 proven 2x2 lerp form) ----
template <int SW, int SH, int DW, bool AXIS, bool INT>
__device__ __forceinline__ void lds_eval(int i, float A, float B, float Cs,
    float D, float E, float Fs, const float2* __restrict__ src,
    float2* __restrict__ dst, int dx0, int dy0)
{
    int ly = i / DW;
    int lx = i - ly * DW;
    int pxi = dx0 + lx, pyi = dy0 + ly;
    float px = (float)pxi, py = (float)pyi;
    float fx = AXIS ? fmaf(A, px, Cs) : fmaf(A, px, fmaf(B, py, Cs));
    float fy = AXIS ? fmaf(E, py, Fs) : fmaf(D, px, fmaf(E, py, Fs));
    float xf = floorf(fx), yf = floorf(fy);
    float wx = fx - xf, wy = fy - yf;
    int x0 = (int)xf, y0 = (int)yf;
    if (!INT) { x0 = min(max(x0, 0), SW - 2); y0 = min(max(y0, 0), SH - 2); }
    const float2* s = src + y0 * SW + x0;
    float2 v00 = s[0], v01 = s[1];        // ds_read2_b64 pair
    float2 v10 = s[SW], v11 = s[SW + 1];
    float2 a0 = lerp2(wx, v00, v01);
    float2 a1 = lerp2(wx, v10, v11);
    float2 val = lerp2(wy, a0, a1);
    if (!INT) {
        if ((unsigned)pxi >= 512u || (unsigned)pyi >= 512u) { val.x = 0.f; val.y = 0.f; }
    }
    dst[i] = val;                          // ds_write_b64
}

template <int SW, int SH, int DW, int DTOT, bool AXIS, bool INT>
__device__ __forceinline__ void stage_lds(int tid, float A, float B, float Cs,
    float D, float E, float Fs, const float2* __restrict__ src,
    float2* __restrict__ dst, int dx0, int dy0)
{
    constexpr int FULL = DTOT / NT;
    constexpr int TAIL = DTOT - FULL * NT;
    #pragma unroll
    for (int k = 0; k < FULL; ++k)
        lds_eval<SW, SH, DW, AXIS, INT>(tid + k * NT, A, B, Cs, D, E, Fs,
                                        src, dst, dx0, dy0);
    if (TAIL && tid < TAIL)
        lds_eval<SW, SH, DW, AXIS, INT>(tid + FULL * NT, A, B, Cs, D, E, Fs,
                                        src, dst, dx0, dy0);
}

// ---- stage 6 (shear): src(R5) -> global, 2 planes ----
template <bool INT>
__device__ __forceinline__ void s6_eval(int ii, const float2* __restrict__ src,
    float* __restrict__ go, int tx0, int ty0, int sx0, int sy0)
{
    int lx = ii & 31, ly = ii >> 5;
    float px = (float)(tx0 + lx), py = (float)(ty0 + ly);
    float fx = fmaf(0.05f, py, -12.775f - (float)sx0) + px;
    float fy = fmaf(-0.03f, px, 7.665f - (float)sy0) + py;
    float xf = floorf(fx), yf = floorf(fy);
    float wx = fx - xf, wy = fy - yf;
    int x0 = (int)xf, y0 = (int)yf;
    if (!INT) { x0 = min(max(x0, 0), W5 - 2); y0 = min(max(y0, 0), H5 - 2); }
    const float2* s = src + y0 * W5 + x0;
    float2 v00 = s[0], v01 = s[1];
    float2 v10 = s[W5], v11 = s[W5 + 1];
    float2 a0 = lerp2(wx, v00, v01);
    float2 a1 = lerp2(wx, v10, v11);
    float2 val = lerp2(wy, a0, a1);
    int gidx = (ty0 + ly) * 512 + tx0 + lx;
    __builtin_nontemporal_store(val.x, &go[gidx]);
    __builtin_nontemporal_store(val.y, &go[HW + gidx]);
}

// ---- interior tile: 4 phases, 3 barriers (s23 fused, s4/s5 round-7 form) ----
__device__ __forceinline__ void img_tile_fast(int tid, const float* __restrict__ gin,
    float* __restrict__ go, int tx0, int ty0, Box R3, Box R4, Box R5,
    float2* bufA, float2* bufB)
{
    // s23: global -> bufB(R3)
    {
        constexpr int FULL = (W3 * H3) / NT;          // 4
        constexpr int TAIL = W3 * H3 - FULL * NT;     // 22
        #pragma unroll
        for (int k = 0; k < FULL; ++k)
            s23_eval(tid + k * NT, gin, bufB, R3.x0, R3.y0);
        if (tid < TAIL) s23_eval(tid + FULL * NT, gin, bufB, R3.x0, R3.y0);
    }
    __syncthreads();
    // s4 (zoom): bufB(R3) -> bufA(R4)
    stage_lds<W3, H3, W4, W4 * H4, true, true>(tid,
        0.9f, 0.0f, 25.55f - (float)R3.x0,
        0.0f, 0.9f, 25.55f - (float)R3.y0, bufB, bufA, R4.x0, R4.y0);
    __syncthreads();
    // s5 (rotate): bufA(R4) -> bufB(R5)
    stage_lds<W4, H4, W5, W5 * H5, false, true>(tid,
        CR, -SR, K5CX - (float)R4.x0,
        SR,  CR, K5CY - (float)R4.y0, bufA, bufB, R5.x0, R5.y0);
    __syncthreads();
    // s6 (shear): bufB(R5) -> global tiles
    #pragma unroll
    for (int k = 0; k < (TS * TS) / NT; ++k)
        s6_eval<true>(tid + k * NT, bufB, go, tx0, ty0, R5.x0, R5.y0);
}

// ---- boundary tile: round-7 5-phase generic pipeline ----
__device__ __forceinline__ void img_tile_gen(int tid, const float* __restrict__ gin,
    float* __restrict__ go, int tx0, int ty0,
    Box R2, Box R3, Box R4, Box R5, float2* bufA, float2* bufB)
{
    {
        constexpr int FULL = (W2 * H2) / NT;
        constexpr int TAIL = W2 * H2 - FULL * NT;
        #pragma unroll
        for (int k = 0; k < FULL; ++k)
            s2_eval_gen(tid + k * NT, gin, bufA, R2.x0, R2.y0);
        if (tid < TAIL) s2_eval_gen(tid + FULL * NT, gin, bufA, R2.x0, R2.y0);
    }
    __syncthreads();
    stage_lds<W2, H2, W3, W3 * H3, true, false>(tid,
        1.1f, 0.0f, -25.55f - (float)R2.x0,
        0.0f, 0.95f, 12.775f - (float)R2.y0, bufA, bufB, R3.x0, R3.y0);
    __syncthreads();
    stage_lds<W3, H3, W4, W4 * H4, true, false>(tid,
        0.9f, 0.0f, 25.55f - (float)R3.x0,
        0.0f, 0.9f, 25.55f - (float)R3.y0, bufB, bufA, R4.x0, R4.y0);
    __syncthreads();
    stage_lds<W4, H4, W5, W5 * H5, false, false>(tid,
        CR, -SR, K5CX - (float)R4.x0,
        SR,  CR, K5CY - (float)R4.y0, bufA, bufB, R5.x0, R5.y0);
    __syncthreads();
    #pragma unroll
    for (int k = 0; k < (TS * TS) / NT; ++k)
        s6_eval<false>(tid + k * NT, bufB, go, tx0, ty0, R5.x0, R5.y0);
}

// Compose the 6 nearest-neighbor integer maps (exact vs sequential resampling).
__global__ void compose_nearest_map(int* __restrict__ map) {
    int p = blockIdx.x * blockDim.x + threadIdx.x;
    if (p >= HW) return;
    const float TH[6][6] = {
        { 1.0f,  0.05f, 0.0f,  -0.03f, 1.0f,  0.0f },   // shear
        { CR,    -SR,   0.0f,   SR,    CR,    0.0f },   // rotate
        { 0.9f,  0.0f,  0.0f,   0.0f,  0.9f,  0.0f },   // zoom
        { 1.1f,  0.0f,  0.0f,   0.0f,  0.95f, 0.0f },   // scale
        { 1.0f,  0.0f,  0.06f,  0.0f,  1.0f, -0.04f },  // translate
        { -1.0f, 0.0f,  0.0f,   0.0f,  1.0f,  0.0f },   // mirror
    };
    int cx = p & 511, cy = p >> 9;
    bool valid = true;
    #pragma unroll
    for (int s = 0; s < 6; ++s) {
        if (!valid) break;
        float x = (cx + 0.5f) * (2.0f / 512.0f) - 1.0f;
        float y = (cy + 0.5f) * (2.0f / 512.0f) - 1.0f;
        float gx = TH[s][0] * x + TH[s][1] * y + TH[s][2];
        float gy = TH[s][3] * x + TH[s][4] * y + TH[s][5];
        float ix = ((gx + 1.0f) * 512.0f - 1.0f) * 0.5f;
        float iy = ((gy + 1.0f) * 512.0f - 1.0f) * 0.5f;
        float xr = rintf(ix), yr = rintf(iy);
        if (xr < 0.0f || xr > 511.0f || yr < 0.0f || yr > 511.0f) valid = false;
        else { cx = (int)xr; cy = (int)yr; }
    }
    map[p] = valid ? (cy * 512 + cx) : -1;
}

// One block per (plane-pair, 32x32 tile).
__global__ __launch_bounds__(NT, 8) void fused_all(
    const float* __restrict__ img, const float* __restrict__ lab,
    const int* __restrict__ map, float* __restrict__ oimg,
    float* __restrict__ olab)
{
    __shared__ float2 bufA[BUFA_SZ];
    __shared__ float2 bufB[BUFB_SZ];
    int tid = threadIdx.x;
    int b = blockIdx.x;
    int group = b >> 8, tile = b & 255;
    int tx0 = (tile & 15) * TS, ty0 = (tile >> 4) * TS;
    int pbase = group * P;
    const float* gin = img + pbase * HW;
    const float* lin = lab + pbase * HW;
    float* go = oimg + pbase * HW;
    float* lo = olab + pbase * HW;

    // ---- label tiles: one map read feeds both planes ----
    #pragma unroll
    for (int k = 0; k < (TS * TS) / NT; ++k) {
        int ii = tid + k * NT;
        int gidx = (ty0 + (ii >> 5)) * 512 + tx0 + (ii & 31);
        int m = map[gidx];
        float v0 = (m >= 0) ? lin[m] : 0.f;
        float v1 = (m >= 0) ? lin[HW + m] : 0.f;
        __builtin_nontemporal_store(v0, &lo[gidx]);
        __builtin_nontemporal_store(v1, &lo[HW + gidx]);
    }

    // ---- region chain (uniform across threads) ----
    Box R6 = {tx0, tx0 + TS - 1, ty0, ty0 + TS - 1};
    Box R5 = back_box(R6, 1.0f, 0.05f, -12.775f, -0.03f, 1.0f, 7.665f);   // shear
    R5.x1 = min(R5.x1, R5.x0 + W5 - 1); R5.y1 = min(R5.y1, R5.y0 + H5 - 1);
    Box R4 = back_box(R5, CR, -SR, K5CX, SR, CR, K5CY);                   // rotate
    R4.x1 = min(R4.x1, R4.x0 + W4 - 1); R4.y1 = min(R4.y1, R4.y0 + H4 - 1);
    Box R3 = back_box(R4, 0.9f, 0.0f, 25.55f, 0.0f, 0.9f, 25.55f);        // zoom
    R3.x1 = min(R3.x1, R3.x0 + W3 - 1); R3.y1 = min(R3.y1, R3.y0 + H3 - 1);
    Box R2 = back_box(R3, 1.1f, 0.0f, -25.55f, 0.0f, 0.95f, 12.775f);     // scale

    bool dead = (R2.x1 < 0 || R2.x0 > 511 || R2.y1 < 0 || R2.y0 > 511)
             || (R3.x1 < 0 || R3.x0 > 511 || R3.y1 < 0 || R3.y0 > 511)
             || (R4.x1 < 0 || R4.x0 > 511 || R4.y1 < 0 || R4.y0 > 511)
             || (R5.x1 < 0 || R5.x0 > 511 || R5.y1 < 0 || R5.y0 > 511);
    if (dead) {
        #pragma unroll
        for (int k = 0; k < (TS * TS) / NT; ++k) {
            int ii = tid + k * NT;
            int gidx = (ty0 + (ii >> 5)) * 512 + tx0 + (ii & 31);
            __builtin_nontemporal_store(0.f, &go[gidx]);
            __builtin_nontemporal_store(0.f, &go[HW + gidx]);
        }
        return;
    }

    // interior: every PADDED region cell has fully-valid taps & coords
    bool interior =
        R2.x0 >= 0 && R2.x0 + W2 - 1 <= 495 && R2.y0 >= 11 && R2.y0 + H2 - 1 <= 511 &&
        R3.x0 >= 0 && R3.x0 + W3 - 1 <= 511 && R3.y0 >= 0 && R3.y0 + H3 - 1 <= 511 &&
        R4.x0 >= 0 && R4.x0 + W4 - 1 <= 511 && R4.y0 >= 0 && R4.y0 + H4 - 1 <= 511 &&
        R5.x0 >= 0 && R5.x0 + W5 - 1 <= 511 && R5.y0 >= 0 && R5.y0 + H5 - 1 <= 511;

    if (interior)
        img_tile_fast(tid, gin, go, tx0, ty0, R3, R4, R5, bufA, bufB);
    else
        img_tile_gen(tid, gin, go, tx0, ty0, R2, R3, R4, R5, bufA, bufB);
}

extern "C" void kernel_launch(void* const* d_in, const int* in_sizes, int n_in,
                              void* d_out, int out_size, void* d_ws, size_t ws_size,
                              hipStream_t stream) {
    const float* img_in = (const float*)d_in[0];
    const float* lab_in = (const float*)d_in[1];
    float* out_img = (float*)d_out;
    float* out_lab = (float*)d_out + TOTAL;
    int* map = (int*)d_ws;

    compose_nearest_map<<<(HW + 255) / 256, 256, 0, stream>>>(map);
    fused_all<<<NGROUP * 256, NT, 0, stream>>>(img_in, lab_in, map, out_img, out_lab);
}